// Round 8
// baseline (1970.973 us; speedup 1.0000x reference)
//
#include <hip/hip_runtime.h>
#include <stdint.h>

// JAX jax_threefry_partitionable=True semantics (verified exact, rounds 1-7).
// Round-8: R7 skeleton, two changes:
//  (1) sim uses a CONTIGUOUS node<->thread mapping (SIMT=512, NPT=20): u-loads 5x float4,
//      p/s stores 30x float4 (staged per 4 nodes), nv reads ds_read_b128 -> ~4.5x fewer
//      VMEM issues/step (R7's 60 scalar stores/thread were the sim's issue-cost floor).
//  (2) k_rand folded into k_scan (first 1160 blocks also compute threefry under the
//      memory shadow; rand is VALU-only, scan is BW-only) -> one fewer launch.
constexpr int NN = 10000;          // nodes
constexpr int EE = 1000;           // hyperedges
constexpr int TT = 30;             // output rows
constexpr int TS = TT - 1;         // simulated steps
constexpr int ROW = NN * 3;        // floats per output row
constexpr int S_OFF = TT * ROW;    // state section offset in d_out
constexpr int CAP_E = 48;          // max nodes per edge (P(>=48) ~ 1e-30)
constexpr int WPR = CAP_E / 2;     // packed uint32 words per edge row
constexpr int PREW = 8;            // words prefetched unconditionally (covers ec<=16, ~97%)
constexpr int SIMT = 512;          // sim block threads (8 waves on one CU)
constexpr int NPT  = 20;           // nodes per thread: 500 x 20 = 10000, 240 B span (16-aligned)
constexpr int RB   = (NN + 255) / 256;  // 40 rand chunks per step

// ---- Threefry-2x32, 20 rounds (exact JAX semantics), host+device ----
__host__ __device__ inline void tf2x32(uint32_t k0, uint32_t k1,
                                       uint32_t x0, uint32_t x1,
                                       uint32_t &o0, uint32_t &o1) {
  uint32_t ks2 = k0 ^ k1 ^ 0x1BD11BDAu;
  x0 += k0; x1 += k1;
#define TFR(r) do { x0 += x1; x1 = (x1 << (r)) | (x1 >> (32 - (r))); x1 ^= x0; } while (0)
  TFR(13); TFR(15); TFR(26); TFR(6);
  x0 += k1;  x1 += ks2 + 1u;
  TFR(17); TFR(29); TFR(16); TFR(24);
  x0 += ks2; x1 += k0 + 2u;
  TFR(13); TFR(15); TFR(26); TFR(6);
  x0 += k0;  x1 += k1 + 3u;
  TFR(17); TFR(29); TFR(16); TFR(24);
  x0 += k1;  x1 += ks2 + 4u;
  TFR(13); TFR(15); TFR(26); TFR(6);
  x0 += ks2; x1 += k0 + 5u;
#undef TFR
  o0 = x0; o1 = x1;
}

__device__ inline float bits_to_uniform(uint32_t bits) {
  float f = __uint_as_float((bits >> 9) | 0x3F800000u) - 1.0f;
  return f < 0.f ? 0.f : f;
}

struct StepKeys { uint32_t k1a[TS], k1b[TS], k2a[TS], k2b[TS]; };

// LDS-only barrier: orders LDS ops across the block WITHOUT draining global stores.
// Safe: all cross-phase deps in k_sim are through LDS; output stores are fire-and-forget.
__device__ inline void bar_lds() {
  asm volatile("s_waitcnt lgkmcnt(0)\n\ts_barrier" ::: "memory");
}

// scan + rand fused. Block b scans H row b; blocks b < TS*RB additionally compute a
// 256-wide slice of the uniforms (VALU work hidden under the scan's HBM stream).
__global__ void k_scanrand(const float* __restrict__ H, int* __restrict__ edge_cnt,
                           uint32_t* __restrict__ edge_words,
                           float* __restrict__ u1, float* __restrict__ u2, StepKeys keys) {
  const int row = blockIdx.x;  // t*EE + e
  const int t = row / EE;
  const int e = row - t * EE;

  // ---- rand side-job (blocks 0..TS*RB-1) ----
  if (row < TS * RB) {
    int rt = row / RB, chunk = row - rt * RB;
    int n = chunk * 256 + threadIdx.x;
    if (n < NN) {
      uint32_t a, b;
      tf2x32(keys.k1a[rt], keys.k1b[rt], 0u, (uint32_t)n, a, b);
      u1[rt * NN + n] = bits_to_uniform(a ^ b);
      tf2x32(keys.k2a[rt], keys.k2b[rt], 0u, (uint32_t)n, a, b);
      u2[rt * NN + n] = bits_to_uniform(a ^ b);
    }
  }

  // ---- scan ----
  __shared__ int cnt;
  __shared__ uint16_t list[CAP_E];
  if (threadIdx.x == 0) cnt = 0;
  __syncthreads();
  const float4* hrow = reinterpret_cast<const float4*>(H + (size_t)row * NN);
  for (int i = threadIdx.x; i < NN / 4; i += blockDim.x) {
    float4 v = hrow[i];
    int b4 = i * 4;
    if (v.x != 0.f) { int p = atomicAdd(&cnt, 1); if (p < CAP_E) list[p] = (uint16_t)(b4 + 0); }
    if (v.y != 0.f) { int p = atomicAdd(&cnt, 1); if (p < CAP_E) list[p] = (uint16_t)(b4 + 1); }
    if (v.z != 0.f) { int p = atomicAdd(&cnt, 1); if (p < CAP_E) list[p] = (uint16_t)(b4 + 2); }
    if (v.w != 0.f) { int p = atomicAdd(&cnt, 1); if (p < CAP_E) list[p] = (uint16_t)(b4 + 3); }
  }
  __syncthreads();
  int c = cnt < CAP_E ? cnt : CAP_E;
  if (threadIdx.x == 0) edge_cnt[row] = c;
  int words = (c + 1) >> 1;
  int wmax = words > PREW ? words : PREW;   // sentinel-pad so sim can prefetch PREW blindly
  if ((int)threadIdx.x < wmax) {
    int j = threadIdx.x;
    uint32_t lo = (2 * j     < c) ? (uint32_t)list[2 * j]     : 0xFFFFu;
    uint32_t hi = (2 * j + 1 < c) ? (uint32_t)list[2 * j + 1] : 0xFFFFu;
    edge_words[((size_t)t * WPR + j) * EE + e] = lo | (hi << 16);
  }
}

// ---- all 29 steps, one workgroup (8 waves); p in regs, s_st/nv in LDS ----
__global__ __launch_bounds__(SIMT, 2)
void k_sim(float* __restrict__ out, const float* __restrict__ x,
           const int* __restrict__ edge_cnt, const uint32_t* __restrict__ edge_words,
           const float* __restrict__ u1, const float* __restrict__ u2,
           const float* __restrict__ beta, const float* __restrict__ gamma_) {
  __shared__ uint8_t s_st[NN];   // 10 KB: state code 0=S 1=I 2=R
  __shared__ int nv[NN];         // 40 KB: per-node two-hop infected count (exact ints)
  const int tid = threadIdx.x;
  const bool owner = (tid < NN / NPT);   // 500 owner threads x 20 contiguous nodes
  const int n0 = tid * NPT;

  float p0[NPT], p1[NPT], p2[NPT], bet[NPT], gam[NPT];
  if (owner) {
    const float4* xv = reinterpret_cast<const float4*>(x + (size_t)n0 * 3);
    float4* o0v = reinterpret_cast<float4*>(out + (size_t)n0 * 3);
    float4* o1v = reinterpret_cast<float4*>(out + S_OFF + (size_t)n0 * 3);
#pragma unroll
    for (int j = 0; j < NPT * 3 / 4; ++j) {        // 15 float4 = 60 floats
      float4 v = xv[j];
      o0v[j] = v; o1v[j] = v;                      // row 0 of both sections = x
      reinterpret_cast<float4*>(p0)[0] = v;        // placeholder (overwritten below)
    }
    const float4* bv = reinterpret_cast<const float4*>(beta + n0);
    const float4* gv = reinterpret_cast<const float4*>(gamma_ + n0);
#pragma unroll
    for (int j = 0; j < NPT / 4; ++j) {
      reinterpret_cast<float4*>(bet)[j] = bv[j];
      reinterpret_cast<float4*>(gam)[j] = gv[j];
    }
    uint32_t codes[NPT / 4];
#pragma unroll
    for (int k = 0; k < NPT; ++k) {
      int n = n0 + k;
      float x0 = x[n * 3 + 0], x1 = x[n * 3 + 1];
      p0[k] = x0; p1[k] = x1; p2[k] = x[n * 3 + 2];
      uint32_t c = (x1 == 1.f) ? 1u : ((x0 == 1.f) ? 0u : 2u);
      if ((k & 3) == 0) codes[k >> 2] = c; else codes[k >> 2] |= c << (8 * (k & 3));
    }
#pragma unroll
    for (int j = 0; j < NPT / 4; ++j)
      reinterpret_cast<uint32_t*>(s_st + n0)[j] = codes[j];
    int4 z = make_int4(0, 0, 0, 0);
#pragma unroll
    for (int j = 0; j < NPT / 4; ++j)
      reinterpret_cast<int4*>(nv + n0)[j] = z;
  }
  bar_lds();

  for (int t = 0; t < TS; ++t) {
    // preload this step's uniforms as float4 (latency hidden behind edge phase)
    float u1r[NPT], u2r[NPT];
    if (owner) {
      const float4* u1v = reinterpret_cast<const float4*>(u1 + (size_t)t * NN + n0);
      const float4* u2v = reinterpret_cast<const float4*>(u2 + (size_t)t * NN + n0);
#pragma unroll
      for (int j = 0; j < NPT / 4; ++j) {
        reinterpret_cast<float4*>(u1r)[j] = u1v[j];
        reinterpret_cast<float4*>(u2r)[j] = u2v[j];
      }
    }

    // edge phase: each thread handles edges {tid, tid+SIMT}; prefetch both upfront
    uint32_t w0[PREW], w1[PREW];
    int ec0 = 0, ec1 = 0;
    const int e1i = tid + SIMT;
    {
      const uint32_t* wb0 = edge_words + (size_t)t * WPR * EE + tid;
      ec0 = edge_cnt[t * EE + tid];                       // tid < 512 < EE always valid
#pragma unroll
      for (int j = 0; j < PREW; ++j) w0[j] = wb0[(size_t)j * EE];
      if (e1i < EE) {
        const uint32_t* wb1 = edge_words + (size_t)t * WPR * EE + e1i;
        ec1 = edge_cnt[t * EE + e1i];
#pragma unroll
        for (int j = 0; j < PREW; ++j) w1[j] = wb1[(size_t)j * EE];
      }
    }
#pragma unroll
    for (int pass = 0; pass < 2; ++pass) {
      int e = pass == 0 ? tid : e1i;
      if (e >= EE) continue;
      int ec = pass == 0 ? ec0 : ec1;
      if (ec > CAP_E) ec = CAP_E;
      const uint32_t* w = pass == 0 ? w0 : w1;
      const uint32_t* wb = edge_words + (size_t)t * WPR * EE + e;
      int words = (ec + 1) >> 1;
      int s = 0;
#pragma unroll
      for (int j = 0; j < PREW; ++j) {
        uint32_t lo = w[j] & 0xFFFFu, hi = w[j] >> 16;
        if (lo != 0xFFFFu) s += (s_st[lo] == 1) ? 1 : 0;
        if (hi != 0xFFFFu) s += (s_st[hi] == 1) ? 1 : 0;
      }
      for (int j = PREW; j < words; ++j) {                // rare (ec > 16)
        uint32_t ww = wb[(size_t)j * EE];
        uint32_t lo = ww & 0xFFFFu, hi = ww >> 16;
        if (lo != 0xFFFFu) s += (s_st[lo] == 1) ? 1 : 0;
        if (hi != 0xFFFFu) s += (s_st[hi] == 1) ? 1 : 0;
      }
      if (s > 0) {
#pragma unroll
        for (int j = 0; j < PREW; ++j) {
          uint32_t lo = w[j] & 0xFFFFu, hi = w[j] >> 16;
          if (lo != 0xFFFFu) atomicAdd(&nv[lo], s);
          if (hi != 0xFFFFu) atomicAdd(&nv[hi], s);
        }
        for (int j = PREW; j < words; ++j) {
          uint32_t ww = wb[(size_t)j * EE];
          uint32_t lo = ww & 0xFFFFu, hi = ww >> 16;
          if (lo != 0xFFFFu) atomicAdd(&nv[lo], s);
          if (hi != 0xFFFFu) atomicAdd(&nv[hi], s);
        }
      }
    }
    bar_lds();  // nv complete

    // node phase: 20 contiguous nodes/thread; stage 4 nodes -> 3 float4 stores each
    if (owner) {
      float* po = out + (size_t)(t + 1) * ROW + (size_t)n0 * 3;
      float* so = out + S_OFF + (size_t)(t + 1) * ROW + (size_t)n0 * 3;
      int nvr[NPT];
      uint32_t str[NPT / 4];
#pragma unroll
      for (int j = 0; j < NPT / 4; ++j) {
        reinterpret_cast<int4*>(nvr)[j] = reinterpret_cast<const int4*>(nv + n0)[j];
        str[j] = reinterpret_cast<const uint32_t*>(s_st + n0)[j];
      }
      int4 z = make_int4(0, 0, 0, 0);
#pragma unroll
      for (int j = 0; j < NPT / 4; ++j)
        reinterpret_cast<int4*>(nv + n0)[j] = z;          // zero for next step
      uint32_t newc[NPT / 4];
      float pst[12], sst[12];
#pragma unroll
      for (int k = 0; k < NPT; ++k) {
        int st = (str[k >> 2] >> (8 * (k & 3))) & 0xFFu;
        float s1 = (st == 1) ? 1.f : 0.f;
        float new_cases = __fmul_rn(bet[k], (float)nvr[k]);
        float new_rec   = __fmul_rn(gam[k], s1);
        float q0 = fminf(1.f, fmaxf(0.f, __fsub_rn(p0[k], new_cases)));
        float q1 = fminf(1.f, fmaxf(0.f, __fsub_rn(__fadd_rn(p1[k], new_cases), new_rec)));
        float q2 = fminf(1.f, fmaxf(0.f, __fadd_rn(p2[k], new_rec)));
        p0[k] = q0; p1[k] = q1; p2[k] = q2;

        bool was_S  = (st == 0);
        bool was_I  = (st == 1);
        bool s_to_I = was_S && (u1r[k] < q1);
        bool i_event = was_I && (u1r[k] < q2);
        bool u2lt   = (u2r[k] < 0.5f);
        bool i_to_R = i_event && u2lt;
        bool i_to_S = i_event && !u2lt;
        bool new_S = (was_S && !s_to_I) || i_to_S;
        bool new_I = s_to_I || (was_I && !i_event);
        bool new_R = (!was_S && !was_I) || i_to_R;
        uint32_t c = new_I ? 1u : (new_S ? 0u : 2u);
        if ((k & 3) == 0) newc[k >> 2] = c; else newc[k >> 2] |= c << (8 * (k & 3));

        int kk = k & 3;
        pst[kk * 3 + 0] = q0; pst[kk * 3 + 1] = q1; pst[kk * 3 + 2] = q2;
        sst[kk * 3 + 0] = new_S ? 1.f : 0.f;
        sst[kk * 3 + 1] = new_I ? 1.f : 0.f;
        sst[kk * 3 + 2] = new_R ? 1.f : 0.f;
        if (kk == 3) {   // 4 nodes staged = 48 B: flush as 3 float4 each
          int g = k >> 2;
          float4* pv = reinterpret_cast<float4*>(po + g * 12);
          float4* sv = reinterpret_cast<float4*>(so + g * 12);
#pragma unroll
          for (int j = 0; j < 3; ++j) {
            pv[j] = reinterpret_cast<float4*>(pst)[j];
            sv[j] = reinterpret_cast<float4*>(sst)[j];
          }
        }
      }
#pragma unroll
      for (int j = 0; j < NPT / 4; ++j)
        reinterpret_cast<uint32_t*>(s_st + n0)[j] = newc[j];
    }
    bar_lds();  // s_st / nv stable before next edge phase
  }
}

extern "C" void kernel_launch(void* const* d_in, const int* in_sizes, int n_in,
                              void* d_out, int out_size, void* d_ws, size_t ws_size,
                              hipStream_t stream) {
  const float* x      = (const float*)d_in[0];
  const float* H      = (const float*)d_in[1];
  const float* beta   = (const float*)d_in[2];
  const float* gamma_ = (const float*)d_in[3];
  float* out = (float*)d_out;

  // key chain: key0 = jax.random.key(42) = (0,42); split(key,3) partitionable:
  // subkey i = threefry(key, (0,i)); carry = subkey 0.
  StepKeys keys;
  uint32_t key0 = 0u, key1 = 42u;
  for (int t = 0; t < TS; ++t) {
    uint32_t a0, b0, a1, b1, a2, b2;
    tf2x32(key0, key1, 0u, 0u, a0, b0);
    tf2x32(key0, key1, 0u, 1u, a1, b1);
    tf2x32(key0, key1, 0u, 2u, a2, b2);
    keys.k1a[t] = a1; keys.k1b[t] = b1; keys.k2a[t] = a2; keys.k2b[t] = b2;
    key0 = a0; key1 = b0;
  }

  // workspace layout (~5.2 MB)
  size_t off = 0;
  auto take = [&](size_t bytes) { size_t o = off; off += (bytes + 255) & ~(size_t)255; return o; };
  size_t o_ec = take((size_t)TS * EE * sizeof(int));
  size_t o_ew = take((size_t)TS * WPR * EE * sizeof(uint32_t));
  size_t o_u1 = take((size_t)TS * NN * sizeof(float));
  size_t o_u2 = take((size_t)TS * NN * sizeof(float));

  int*      edge_cnt   = (int*)((char*)d_ws + o_ec);
  uint32_t* edge_words = (uint32_t*)((char*)d_ws + o_ew);
  float*    u1         = (float*)((char*)d_ws + o_u1);
  float*    u2         = (float*)((char*)d_ws + o_u2);

  k_scanrand<<<TS * EE, 256, 0, stream>>>(H, edge_cnt, edge_words, u1, u2, keys);
  k_sim<<<1, SIMT, 0, stream>>>(out, x, edge_cnt, edge_words, u1, u2, beta, gamma_);
}

// Round 9
// 1725.830 us; speedup vs baseline: 1.1420x; 1.1420x over previous
//
#include <hip/hip_runtime.h>
#include <stdint.h>

// JAX jax_threefry_partitionable=True semantics (verified exact, rounds 1-8).
// Round-9: exact R7 revert (best: 1753us) + two register-neutral tweaks:
//  (a) rand fused into scan (R8 change #2 - innocent; saves one launch). R8's +217us
//      regression was k_sim's ~350-VGPR contiguous-mapping rewrite spilling to scratch;
//      that rewrite is reverted wholesale.
//  (b) u1/u2 interleaved as float2 uv[t][n]: sim's u-preload = 10 dwordx2 from one
//      stream instead of 20 dwords from two distant pages. Same register count.
constexpr int NN = 10000;          // nodes
constexpr int EE = 1000;           // hyperedges
constexpr int TT = 30;             // output rows
constexpr int TS = TT - 1;         // simulated steps
constexpr int ROW = NN * 3;        // floats per output row
constexpr int S_OFF = TT * ROW;    // state section offset in d_out
constexpr int CAP_E = 48;          // max nodes per edge (P(>=48) ~ 1e-30)
constexpr int WPR = CAP_E / 2;     // packed uint32 words per edge row
constexpr int PREW = 8;            // words prefetched unconditionally (covers ec<=16, ~97%)
constexpr int SIMT = 1024;         // sim block threads (16 waves on one CU)
constexpr int NPT  = 10;           // nodes per thread, strided mapping n = tid + k*SIMT
constexpr int RB   = (NN + 255) / 256;  // 40 rand chunks per step

// ---- Threefry-2x32, 20 rounds (exact JAX semantics), host+device ----
__host__ __device__ inline void tf2x32(uint32_t k0, uint32_t k1,
                                       uint32_t x0, uint32_t x1,
                                       uint32_t &o0, uint32_t &o1) {
  uint32_t ks2 = k0 ^ k1 ^ 0x1BD11BDAu;
  x0 += k0; x1 += k1;
#define TFR(r) do { x0 += x1; x1 = (x1 << (r)) | (x1 >> (32 - (r))); x1 ^= x0; } while (0)
  TFR(13); TFR(15); TFR(26); TFR(6);
  x0 += k1;  x1 += ks2 + 1u;
  TFR(17); TFR(29); TFR(16); TFR(24);
  x0 += ks2; x1 += k0 + 2u;
  TFR(13); TFR(15); TFR(26); TFR(6);
  x0 += k0;  x1 += k1 + 3u;
  TFR(17); TFR(29); TFR(16); TFR(24);
  x0 += k1;  x1 += ks2 + 4u;
  TFR(13); TFR(15); TFR(26); TFR(6);
  x0 += ks2; x1 += k0 + 5u;
#undef TFR
  o0 = x0; o1 = x1;
}

__device__ inline float bits_to_uniform(uint32_t bits) {
  float f = __uint_as_float((bits >> 9) | 0x3F800000u) - 1.0f;
  return f < 0.f ? 0.f : f;
}

struct StepKeys { uint32_t k1a[TS], k1b[TS], k2a[TS], k2b[TS]; };

// LDS-only barrier: orders LDS ops across the block WITHOUT draining global stores
// (vmcnt). Safe: all cross-phase deps in k_sim are through LDS; output stores are
// fire-and-forget and drain at s_endpgm.
__device__ inline void bar_lds() {
  asm volatile("s_waitcnt lgkmcnt(0)\n\ts_barrier" ::: "memory");
}

// scan + rand fused. Block b scans H row b; blocks b < TS*RB additionally compute a
// 256-wide slice of the uniforms (VALU-only work hidden under the scan's HBM stream).
__global__ void k_scanrand(const float* __restrict__ H, int* __restrict__ edge_cnt,
                           uint32_t* __restrict__ edge_words,
                           float2* __restrict__ uv, StepKeys keys) {
  const int row = blockIdx.x;  // t*EE + e
  const int t = row / EE;
  const int e = row - t * EE;

  // ---- rand side-job (blocks 0..TS*RB-1): uv[rt][n] = (u1, u2) interleaved ----
  if (row < TS * RB) {
    int rt = row / RB, chunk = row - rt * RB;
    int n = chunk * 256 + threadIdx.x;
    if (n < NN) {
      uint32_t a, b;
      float2 v;
      tf2x32(keys.k1a[rt], keys.k1b[rt], 0u, (uint32_t)n, a, b);
      v.x = bits_to_uniform(a ^ b);
      tf2x32(keys.k2a[rt], keys.k2b[rt], 0u, (uint32_t)n, a, b);
      v.y = bits_to_uniform(a ^ b);
      uv[(size_t)rt * NN + n] = v;
    }
  }

  // ---- scan ----
  __shared__ int cnt;
  __shared__ uint16_t list[CAP_E];
  if (threadIdx.x == 0) cnt = 0;
  __syncthreads();
  const float4* hrow = reinterpret_cast<const float4*>(H + (size_t)row * NN);
  for (int i = threadIdx.x; i < NN / 4; i += blockDim.x) {
    float4 v = hrow[i];
    int b4 = i * 4;
    if (v.x != 0.f) { int p = atomicAdd(&cnt, 1); if (p < CAP_E) list[p] = (uint16_t)(b4 + 0); }
    if (v.y != 0.f) { int p = atomicAdd(&cnt, 1); if (p < CAP_E) list[p] = (uint16_t)(b4 + 1); }
    if (v.z != 0.f) { int p = atomicAdd(&cnt, 1); if (p < CAP_E) list[p] = (uint16_t)(b4 + 2); }
    if (v.w != 0.f) { int p = atomicAdd(&cnt, 1); if (p < CAP_E) list[p] = (uint16_t)(b4 + 3); }
  }
  __syncthreads();
  int c = cnt < CAP_E ? cnt : CAP_E;
  if (threadIdx.x == 0) edge_cnt[row] = c;
  int words = (c + 1) >> 1;
  int wmax = words > PREW ? words : PREW;   // sentinel-pad so sim can prefetch PREW blindly
  if ((int)threadIdx.x < wmax) {
    int j = threadIdx.x;
    uint32_t lo = (2 * j     < c) ? (uint32_t)list[2 * j]     : 0xFFFFu;
    uint32_t hi = (2 * j + 1 < c) ? (uint32_t)list[2 * j + 1] : 0xFFFFu;
    edge_words[((size_t)t * WPR + j) * EE + e] = lo | (hi << 16);
  }
}

// ---- all 29 steps, one workgroup; p in regs, s_st/nv in LDS (R7 structure) ----
__global__ __launch_bounds__(SIMT, 4)
void k_sim(float* __restrict__ out, const float* __restrict__ x,
           const int* __restrict__ edge_cnt, const uint32_t* __restrict__ edge_words,
           const float2* __restrict__ uv,
           const float* __restrict__ beta, const float* __restrict__ gamma_) {
  __shared__ uint8_t s_st[NN];   // 10 KB: state code 0=S 1=I 2=R
  __shared__ int nv[NN];         // 40 KB: per-node two-hop infected count (exact ints)
  const int tid = threadIdx.x;

  float p0[NPT], p1[NPT], p2[NPT], bet[NPT], gam[NPT];
#pragma unroll
  for (int k = 0; k < NPT; ++k) {
    int n = tid + k * SIMT;
    if (n < NN) {
      float x0 = x[n * 3 + 0], x1 = x[n * 3 + 1], x2 = x[n * 3 + 2];
      p0[k] = x0; p1[k] = x1; p2[k] = x2;
      s_st[n] = (x1 == 1.f) ? 1 : ((x0 == 1.f) ? 0 : 2);
      nv[n] = 0;
      bet[k] = beta[n]; gam[k] = gamma_[n];
      // row 0 of both output sections = x (fire-and-forget)
      out[n * 3 + 0] = x0; out[n * 3 + 1] = x1; out[n * 3 + 2] = x2;
      out[S_OFF + n * 3 + 0] = x0; out[S_OFF + n * 3 + 1] = x1; out[S_OFF + n * 3 + 2] = x2;
    }
  }
  bar_lds();

  for (int t = 0; t < TS; ++t) {
    // preload this step's uniforms (10x dwordx2; latency hidden behind edge phase)
    float u1r[NPT], u2r[NPT];
#pragma unroll
    for (int k = 0; k < NPT; ++k) {
      int n = tid + k * SIMT;
      if (n < NN) {
        float2 v = uv[(size_t)t * NN + n];
        u1r[k] = v.x; u2r[k] = v.y;
      }
    }

    // edge phase: s = #infected members; scatter s into members' nv (skip if s==0)
    if (tid < EE) {
      const uint32_t* wb = edge_words + (size_t)t * WPR * EE + tid;
      int ec = edge_cnt[t * EE + tid]; if (ec > CAP_E) ec = CAP_E;
      uint32_t w[PREW];
#pragma unroll
      for (int j = 0; j < PREW; ++j) w[j] = wb[(size_t)j * EE];  // independent, one latency
      int words = (ec + 1) >> 1;
      int s = 0;
#pragma unroll
      for (int j = 0; j < PREW; ++j) {
        uint32_t lo = w[j] & 0xFFFFu, hi = w[j] >> 16;
        if (lo != 0xFFFFu) s += (s_st[lo] == 1) ? 1 : 0;
        if (hi != 0xFFFFu) s += (s_st[hi] == 1) ? 1 : 0;
      }
      for (int j = PREW; j < words; ++j) {  // rare (ec > 16, ~3% of edges)
        uint32_t ww = wb[(size_t)j * EE];
        uint32_t lo = ww & 0xFFFFu, hi = ww >> 16;
        if (lo != 0xFFFFu) s += (s_st[lo] == 1) ? 1 : 0;
        if (hi != 0xFFFFu) s += (s_st[hi] == 1) ? 1 : 0;
      }
      if (s > 0) {  // adding 0 is a no-op: exactness unaffected
#pragma unroll
        for (int j = 0; j < PREW; ++j) {
          uint32_t lo = w[j] & 0xFFFFu, hi = w[j] >> 16;
          if (lo != 0xFFFFu) atomicAdd(&nv[lo], s);
          if (hi != 0xFFFFu) atomicAdd(&nv[hi], s);
        }
        for (int j = PREW; j < words; ++j) {
          uint32_t ww = wb[(size_t)j * EE];
          uint32_t lo = ww & 0xFFFFu, hi = ww >> 16;
          if (lo != 0xFFFFu) atomicAdd(&nv[lo], s);
          if (hi != 0xFFFFu) atomicAdd(&nv[hi], s);
        }
      }
    }
    bar_lds();  // nv complete (LDS ordering only; output stores keep draining)

    // node phase: advance p in regs, draw transitions, write output rows, zero nv
    float* po = out + (size_t)(t + 1) * ROW;
    float* so = out + S_OFF + (size_t)(t + 1) * ROW;
#pragma unroll
    for (int k = 0; k < NPT; ++k) {
      int n = tid + k * SIMT;
      if (n < NN) {
        int st = s_st[n];
        int v = nv[n];
        nv[n] = 0;  // zero for next step (protected by the trailing bar_lds)
        float s1 = (st == 1) ? 1.f : 0.f;
        float new_cases = __fmul_rn(bet[k], (float)v);
        float new_rec   = __fmul_rn(gam[k], s1);
        float q0 = fminf(1.f, fmaxf(0.f, __fsub_rn(p0[k], new_cases)));
        float q1 = fminf(1.f, fmaxf(0.f, __fsub_rn(__fadd_rn(p1[k], new_cases), new_rec)));
        float q2 = fminf(1.f, fmaxf(0.f, __fadd_rn(p2[k], new_rec)));
        p0[k] = q0; p1[k] = q1; p2[k] = q2;

        bool was_S  = (st == 0);
        bool was_I  = (st == 1);
        bool s_to_I = was_S && (u1r[k] < q1);
        bool i_event = was_I && (u1r[k] < q2);
        bool u2lt   = (u2r[k] < 0.5f);
        bool i_to_R = i_event && u2lt;
        bool i_to_S = i_event && !u2lt;
        bool new_S = (was_S && !s_to_I) || i_to_S;
        bool new_I = s_to_I || (was_I && !i_event);
        bool new_R = (!was_S && !was_I) || i_to_R;

        po[n * 3 + 0] = q0; po[n * 3 + 1] = q1; po[n * 3 + 2] = q2;
        so[n * 3 + 0] = new_S ? 1.f : 0.f;
        so[n * 3 + 1] = new_I ? 1.f : 0.f;
        so[n * 3 + 2] = new_R ? 1.f : 0.f;
        s_st[n] = new_I ? 1 : (new_S ? 0 : 2);
      }
    }
    bar_lds();  // s_st / nv stable before next edge phase
  }
}

extern "C" void kernel_launch(void* const* d_in, const int* in_sizes, int n_in,
                              void* d_out, int out_size, void* d_ws, size_t ws_size,
                              hipStream_t stream) {
  const float* x      = (const float*)d_in[0];
  const float* H      = (const float*)d_in[1];
  const float* beta   = (const float*)d_in[2];
  const float* gamma_ = (const float*)d_in[3];
  float* out = (float*)d_out;

  // key chain: key0 = jax.random.key(42) = (0,42); split(key,3) partitionable:
  // subkey i = threefry(key, (0,i)); carry = subkey 0.
  StepKeys keys;
  uint32_t key0 = 0u, key1 = 42u;
  for (int t = 0; t < TS; ++t) {
    uint32_t a0, b0, a1, b1, a2, b2;
    tf2x32(key0, key1, 0u, 0u, a0, b0);
    tf2x32(key0, key1, 0u, 1u, a1, b1);
    tf2x32(key0, key1, 0u, 2u, a2, b2);
    keys.k1a[t] = a1; keys.k1b[t] = b1; keys.k2a[t] = a2; keys.k2b[t] = b2;
    key0 = a0; key1 = b0;
  }

  // workspace layout (~5.2 MB)
  size_t off = 0;
  auto take = [&](size_t bytes) { size_t o = off; off += (bytes + 255) & ~(size_t)255; return o; };
  size_t o_ec = take((size_t)TS * EE * sizeof(int));
  size_t o_ew = take((size_t)TS * WPR * EE * sizeof(uint32_t));
  size_t o_uv = take((size_t)TS * NN * sizeof(float2));

  int*      edge_cnt   = (int*)((char*)d_ws + o_ec);
  uint32_t* edge_words = (uint32_t*)((char*)d_ws + o_ew);
  float2*   uv         = (float2*)((char*)d_ws + o_uv);

  k_scanrand<<<TS * EE, 256, 0, stream>>>(H, edge_cnt, edge_words, uv, keys);
  k_sim<<<1, SIMT, 0, stream>>>(out, x, edge_cnt, edge_words, uv, beta, gamma_);
}

// Round 10
// 1604.815 us; speedup vs baseline: 1.2282x; 1.0754x over previous
//
#include <hip/hip_runtime.h>
#include <stdint.h>

// JAX jax_threefry_partitionable=True semantics (verified exact, rounds 1-9).
// Round-10: producer/consumer fusion done RIGHT. R6 failed because 29000 RELEASE
// atomics (buffer_wbl2 per block) + ACQUIRE spins (L2 invalidates) throttled scan to
// 585 GB/s. Here ALL cross-block traffic uses RELAXED device-scope atomics that hit the
// coherent point (MALL / Infinity Cache) directly: producers publish edge words/counts/
// uniforms via fire-and-forget __hip_atomic_store (write-through), drain with
// __syncthreads' implicit vmcnt(0), then RELAXED fetch_add on cnt[t]; the sim block
// spins on cnt[t] with RELAXED loads (no cache invalidates). Sim = R9 structure
// (1024 thr, NPT=10, 8-word register prefetch), with state packed into bits 16-17 of
// the nv LDS word (sum <= 48000 << 2^16: adds can never carry into the state bits).
constexpr int NN = 10000;          // nodes
constexpr int EE = 1000;           // hyperedges
constexpr int TT = 30;             // output rows
constexpr int TS = TT - 1;         // simulated steps
constexpr int ROW = NN * 3;        // floats per output row
constexpr int S_OFF = TT * ROW;    // state section offset in d_out
constexpr int CAP_E = 48;          // max nodes per edge (P(>=48) ~ 1e-30)
constexpr int WPR = CAP_E / 2;     // packed uint32 words per edge row
constexpr int PREW = 8;            // words prefetched unconditionally (covers ec<=16, ~97%)
constexpr int SIMT = 1024;         // block size (16 waves)
constexpr int NPT  = 10;           // nodes per thread, strided mapping n = tid + k*SIMT
constexpr int RBLK = (NN + SIMT - 1) / SIMT;  // 10 rand-duty blocks per step

// ---- Threefry-2x32, 20 rounds (exact JAX semantics), host+device ----
__host__ __device__ inline void tf2x32(uint32_t k0, uint32_t k1,
                                       uint32_t x0, uint32_t x1,
                                       uint32_t &o0, uint32_t &o1) {
  uint32_t ks2 = k0 ^ k1 ^ 0x1BD11BDAu;
  x0 += k0; x1 += k1;
#define TFR(r) do { x0 += x1; x1 = (x1 << (r)) | (x1 >> (32 - (r))); x1 ^= x0; } while (0)
  TFR(13); TFR(15); TFR(26); TFR(6);
  x0 += k1;  x1 += ks2 + 1u;
  TFR(17); TFR(29); TFR(16); TFR(24);
  x0 += ks2; x1 += k0 + 2u;
  TFR(13); TFR(15); TFR(26); TFR(6);
  x0 += k0;  x1 += k1 + 3u;
  TFR(17); TFR(29); TFR(16); TFR(24);
  x0 += k1;  x1 += ks2 + 4u;
  TFR(13); TFR(15); TFR(26); TFR(6);
  x0 += ks2; x1 += k0 + 5u;
#undef TFR
  o0 = x0; o1 = x1;
}

__device__ inline float bits_to_uniform(uint32_t bits) {
  float f = __uint_as_float((bits >> 9) | 0x3F800000u) - 1.0f;
  return f < 0.f ? 0.f : f;
}

struct StepKeys { uint32_t k1a[TS], k1b[TS], k2a[TS], k2b[TS]; };

// LDS-only barrier: orders LDS ops without draining global stores (vmcnt).
__device__ inline void bar_lds() {
  asm volatile("s_waitcnt lgkmcnt(0)\n\ts_barrier" ::: "memory");
}

#define ALD(p)    __hip_atomic_load((p),  __ATOMIC_RELAXED, __HIP_MEMORY_SCOPE_AGENT)
#define AST(p, v) __hip_atomic_store((p), (v), __ATOMIC_RELAXED, __HIP_MEMORY_SCOPE_AGENT)

// cnt is in d_ws (poisoned 0xAA every replay): must be zeroed before k_fused.
__global__ void k_zero(unsigned* __restrict__ cnt) {
  if (threadIdx.x < TS) cnt[threadIdx.x] = 0u;
}

__global__ __launch_bounds__(SIMT, 4)
void k_fused(const float* __restrict__ H,
             int* __restrict__ edge_cnt, uint32_t* __restrict__ edge_words,
             unsigned long long* __restrict__ uv, unsigned* __restrict__ cnt,
             const float* __restrict__ x,
             const float* __restrict__ beta, const float* __restrict__ gamma_,
             float* __restrict__ out, StepKeys keys) {
  const int tid = threadIdx.x;

  if (blockIdx.x > 0) {
    // ---------------- scan role: one (t,e) row of H ----------------
    const int row = blockIdx.x - 1;
    const int t = row / EE;
    const int e = row - t * EE;

    // rand duty: first RBLK blocks of each step publish that step's uniforms
    if (e < RBLK) {
      int n = e * SIMT + tid;
      if (n < NN) {
        uint32_t a, b;
        tf2x32(keys.k1a[t], keys.k1b[t], 0u, (uint32_t)n, a, b);
        uint32_t b1 = __float_as_uint(bits_to_uniform(a ^ b));
        tf2x32(keys.k2a[t], keys.k2b[t], 0u, (uint32_t)n, a, b);
        uint32_t b2 = __float_as_uint(bits_to_uniform(a ^ b));
        unsigned long long raw = (unsigned long long)b1 | ((unsigned long long)b2 << 32);
        AST(&uv[(size_t)t * NN + n], raw);
      }
    }

    __shared__ int scnt;
    __shared__ uint16_t list[CAP_E];
    if (tid == 0) scnt = 0;
    __syncthreads();
    // 2500 float4 per row; 3-deep upfront loads for MLP (one latency, not 2.5)
    const float4* hrow = reinterpret_cast<const float4*>(H + (size_t)row * NN);
    float4 v0 = hrow[tid];                     // tid < 1024 < 2500
    float4 v1 = hrow[tid + 1024];              // tid+1024 <= 2047 < 2500
    float4 v2 = make_float4(0.f, 0.f, 0.f, 0.f);
    const bool has2 = tid + 2048 < NN / 4;     // tid < 452
    if (has2) v2 = hrow[tid + 2048];
#define PROC(v, b4) do { \
    if ((v).x != 0.f) { int p = atomicAdd(&scnt, 1); if (p < CAP_E) list[p] = (uint16_t)((b4) + 0); } \
    if ((v).y != 0.f) { int p = atomicAdd(&scnt, 1); if (p < CAP_E) list[p] = (uint16_t)((b4) + 1); } \
    if ((v).z != 0.f) { int p = atomicAdd(&scnt, 1); if (p < CAP_E) list[p] = (uint16_t)((b4) + 2); } \
    if ((v).w != 0.f) { int p = atomicAdd(&scnt, 1); if (p < CAP_E) list[p] = (uint16_t)((b4) + 3); } \
  } while (0)
    PROC(v0, 4 * tid);
    PROC(v1, 4 * (tid + 1024));
    if (has2) PROC(v2, 4 * (tid + 2048));
#undef PROC
    __syncthreads();
    int c = scnt < CAP_E ? scnt : CAP_E;
    if (tid == 0) AST(&edge_cnt[row], c);
    int words = (c + 1) >> 1;
    int wmax = words > PREW ? words : PREW;    // sentinel-pad so sim prefetches blindly
    if (tid < wmax) {
      uint32_t lo = (2 * tid     < c) ? (uint32_t)list[2 * tid]     : 0xFFFFu;
      uint32_t hi = (2 * tid + 1 < c) ? (uint32_t)list[2 * tid + 1] : 0xFFFFu;
      AST(&edge_words[((size_t)t * WPR + tid) * EE + e], lo | (hi << 16));
    }
    __syncthreads();  // compiler emits s_waitcnt vmcnt(0) here: all atomic stores done
    if (tid == 0)
      __hip_atomic_fetch_add(&cnt[t], 1u, __ATOMIC_RELAXED, __HIP_MEMORY_SCOPE_AGENT);
    return;
  }

  // ---------------- sim role (block 0, one CU) ----------------
  // nvst[n]: bits 0-15 = two-hop infected count (exact ints), bits 16-17 = state code.
  __shared__ int nvst[NN];   // 40 KB

  float p0[NPT], p1[NPT], p2[NPT], bet[NPT], gam[NPT];
#pragma unroll
  for (int k = 0; k < NPT; ++k) {
    int n = tid + k * SIMT;
    if (n < NN) {
      float x0 = x[n * 3 + 0], x1 = x[n * 3 + 1], x2 = x[n * 3 + 2];
      p0[k] = x0; p1[k] = x1; p2[k] = x2;
      int st = (x1 == 1.f) ? 1 : ((x0 == 1.f) ? 0 : 2);
      nvst[n] = st << 16;
      bet[k] = beta[n]; gam[k] = gamma_[n];
      out[n * 3 + 0] = x0; out[n * 3 + 1] = x1; out[n * 3 + 2] = x2;
      out[S_OFF + n * 3 + 0] = x0; out[S_OFF + n * 3 + 1] = x1; out[S_OFF + n * 3 + 2] = x2;
    }
  }
  bar_lds();

  for (int t = 0; t < TS; ++t) {
    // wait for all 1000 producer blocks of step t (relaxed spin: no cache ops)
    if (tid == 0) {
      while (ALD(&cnt[t]) < (unsigned)EE) __builtin_amdgcn_s_sleep(8);
    }
    bar_lds();  // barrier A: flag seen; also orders prev node-phase nvst writes

    // preload uniforms for step t (now published) - 10 independent 8B MALL loads
    float u1r[NPT], u2r[NPT];
#pragma unroll
    for (int k = 0; k < NPT; ++k) {
      int n = tid + k * SIMT;
      if (n < NN) {
        unsigned long long raw = ALD(&uv[(size_t)t * NN + n]);
        u1r[k] = __uint_as_float((uint32_t)raw);
        u2r[k] = __uint_as_float((uint32_t)(raw >> 32));
      }
    }

    // edge phase: s = #infected members; scatter s into members' nvst low bits
    if (tid < EE) {
      const uint32_t* wb = edge_words + (size_t)t * WPR * EE + tid;
      int ec = ALD(&edge_cnt[t * EE + tid]); if (ec > CAP_E) ec = CAP_E;
      uint32_t w[PREW];
#pragma unroll
      for (int j = 0; j < PREW; ++j) w[j] = ALD(&wb[(size_t)j * EE]);  // independent
      int words = (ec + 1) >> 1;
      int s = 0;
#pragma unroll
      for (int j = 0; j < PREW; ++j) {
        uint32_t lo = w[j] & 0xFFFFu, hi = w[j] >> 16;
        if (lo != 0xFFFFu) s += ((nvst[lo] >> 16) == 1) ? 1 : 0;
        if (hi != 0xFFFFu) s += ((nvst[hi] >> 16) == 1) ? 1 : 0;
      }
      for (int j = PREW; j < words; ++j) {   // rare tail (ec > 16)
        uint32_t ww = ALD(&wb[(size_t)j * EE]);
        uint32_t lo = ww & 0xFFFFu, hi = ww >> 16;
        if (lo != 0xFFFFu) s += ((nvst[lo] >> 16) == 1) ? 1 : 0;
        if (hi != 0xFFFFu) s += ((nvst[hi] >> 16) == 1) ? 1 : 0;
      }
      if (s > 0) {  // adds can't carry into bit 16 (max sum 48000 < 65536)
#pragma unroll
        for (int j = 0; j < PREW; ++j) {
          uint32_t lo = w[j] & 0xFFFFu, hi = w[j] >> 16;
          if (lo != 0xFFFFu) atomicAdd(&nvst[lo], s);
          if (hi != 0xFFFFu) atomicAdd(&nvst[hi], s);
        }
        for (int j = PREW; j < words; ++j) {
          uint32_t ww = ALD(&wb[(size_t)j * EE]);
          uint32_t lo = ww & 0xFFFFu, hi = ww >> 16;
          if (lo != 0xFFFFu) atomicAdd(&nvst[lo], s);
          if (hi != 0xFFFFu) atomicAdd(&nvst[hi], s);
        }
      }
    }
    bar_lds();  // barrier B: nvst complete

    // node phase: advance p in regs, draw transitions, write rows, reset nvst
    float* po = out + (size_t)(t + 1) * ROW;
    float* so = out + S_OFF + (size_t)(t + 1) * ROW;
#pragma unroll
    for (int k = 0; k < NPT; ++k) {
      int n = tid + k * SIMT;
      if (n < NN) {
        int wv = nvst[n];
        int v  = wv & 0xFFFF;
        int st = wv >> 16;
        float s1 = (st == 1) ? 1.f : 0.f;
        float new_cases = __fmul_rn(bet[k], (float)v);
        float new_rec   = __fmul_rn(gam[k], s1);
        float q0 = fminf(1.f, fmaxf(0.f, __fsub_rn(p0[k], new_cases)));
        float q1 = fminf(1.f, fmaxf(0.f, __fsub_rn(__fadd_rn(p1[k], new_cases), new_rec)));
        float q2 = fminf(1.f, fmaxf(0.f, __fadd_rn(p2[k], new_rec)));
        p0[k] = q0; p1[k] = q1; p2[k] = q2;

        bool was_S  = (st == 0);
        bool was_I  = (st == 1);
        bool s_to_I = was_S && (u1r[k] < q1);
        bool i_event = was_I && (u1r[k] < q2);
        bool u2lt   = (u2r[k] < 0.5f);
        bool i_to_R = i_event && u2lt;
        bool i_to_S = i_event && !u2lt;
        bool new_S = (was_S && !s_to_I) || i_to_S;
        bool new_I = s_to_I || (was_I && !i_event);
        bool new_R = (!was_S && !was_I) || i_to_R;

        po[n * 3 + 0] = q0; po[n * 3 + 1] = q1; po[n * 3 + 2] = q2;
        so[n * 3 + 0] = new_S ? 1.f : 0.f;
        so[n * 3 + 1] = new_I ? 1.f : 0.f;
        so[n * 3 + 2] = new_R ? 1.f : 0.f;
        nvst[n] = (new_I ? 1 : (new_S ? 0 : 2)) << 16;  // reset count + new state
      }
    }
    // next iteration's barrier A orders these nvst writes vs next edge phase
  }
}

extern "C" void kernel_launch(void* const* d_in, const int* in_sizes, int n_in,
                              void* d_out, int out_size, void* d_ws, size_t ws_size,
                              hipStream_t stream) {
  const float* x      = (const float*)d_in[0];
  const float* H      = (const float*)d_in[1];
  const float* beta   = (const float*)d_in[2];
  const float* gamma_ = (const float*)d_in[3];
  float* out = (float*)d_out;

  // key chain: key0 = jax.random.key(42) = (0,42); split(key,3) partitionable:
  // subkey i = threefry(key, (0,i)); carry = subkey 0.
  StepKeys keys;
  uint32_t key0 = 0u, key1 = 42u;
  for (int t = 0; t < TS; ++t) {
    uint32_t a0, b0, a1, b1, a2, b2;
    tf2x32(key0, key1, 0u, 0u, a0, b0);
    tf2x32(key0, key1, 0u, 1u, a1, b1);
    tf2x32(key0, key1, 0u, 2u, a2, b2);
    keys.k1a[t] = a1; keys.k1b[t] = b1; keys.k2a[t] = a2; keys.k2b[t] = b2;
    key0 = a0; key1 = b0;
  }

  // workspace layout (~5.2 MB)
  size_t off = 0;
  auto take = [&](size_t bytes) { size_t o = off; off += (bytes + 255) & ~(size_t)255; return o; };
  size_t o_ec = take((size_t)TS * EE * sizeof(int));
  size_t o_ew = take((size_t)TS * WPR * EE * sizeof(uint32_t));
  size_t o_uv = take((size_t)TS * NN * sizeof(unsigned long long));
  size_t o_ct = take((size_t)TS * sizeof(unsigned));

  int*      edge_cnt   = (int*)((char*)d_ws + o_ec);
  uint32_t* edge_words = (uint32_t*)((char*)d_ws + o_ew);
  unsigned long long* uv = (unsigned long long*)((char*)d_ws + o_uv);
  unsigned* cnt        = (unsigned*)((char*)d_ws + o_ct);

  k_zero<<<1, 64, 0, stream>>>(cnt);
  k_fused<<<1 + TS * EE, SIMT, 0, stream>>>(H, edge_cnt, edge_words, uv, cnt,
                                            x, beta, gamma_, out, keys);
}